// Round 3
// baseline (67.431 us; speedup 1.0000x reference)
//
#include <hip/hip_runtime.h>
#include <cfloat>

#define BB 32
#define TT 4096
#define HH 512
#define KSZ 11
#define PAD 5
#define TCHUNK 64
#define NCHUNK (TT / TCHUNK)             // 64
#define NWAVES 4
#define ROWS_PER_WAVE (TCHUNK / NWAVES)  // 16

typedef float f32x4 __attribute__((ext_vector_type(4)));

__device__ __forceinline__ f32x4 ntload(const float* p) {
    return __builtin_nontemporal_load((const f32x4*)p);
}

// Pass 1: per (batch, T-chunk) block. Computes pax (stores to ws), and an
// online-softmax partial (m, l, acc[H]) over its chunk, combined across the
// block's 4 waves into one partial per block.
__global__ __launch_bounds__(256, 8) void attn_pass1(
    const float* __restrict__ eh, const float* __restrict__ dhx,
    const float* __restrict__ ax, const float* __restrict__ conv_w,
    const float* __restrict__ conv_b,
    float* __restrict__ pax_ws, float* __restrict__ part_m,
    float* __restrict__ part_l, float* __restrict__ part_acc)
{
    const int bid  = blockIdx.x;
    const int b    = bid / NCHUNK;
    const int c    = bid % NCHUNK;
    const int tid  = threadIdx.x;
    const int wave = tid >> 6;
    const int lane = tid & 63;

    __shared__ float s_loc[TCHUNK];
    __shared__ float s_pax[TCHUNK];
    __shared__ float red_m[NWAVES], red_l[NWAVES];
    __shared__ float red_acc[NWAVES][HH];   // 8 KB

    // location bias (11-tap 'same' cross-correlation) for this chunk
    if (tid < TCHUNK) {
        const int t = c * TCHUNK + tid;
        float locv = conv_b[0];
        #pragma unroll
        for (int k = 0; k < KSZ; ++k) {
            const int ts = t + k - PAD;
            const float v = (ts >= 0 && ts < TT) ? ax[b * TT + ts] : 0.0f;
            locv = fmaf(v, conv_w[k], locv);
        }
        s_loc[tid] = locv;
    }

    // per-lane dhx fragment: h = lane*8 .. lane*8+7
    const float* dpp = dhx + (size_t)b * HH + lane * 8;
    const f32x4 d0 = *(const f32x4*)dpp;
    const f32x4 d1 = *(const f32x4*)(dpp + 4);

    __syncthreads();

    float m = -FLT_MAX, l = 0.0f;
    float acc[8];
    #pragma unroll
    for (int j = 0; j < 8; ++j) acc[j] = 0.0f;

    const int t0 = c * TCHUNK + wave * ROWS_PER_WAVE;
    const float* baseA = eh + ((size_t)b * TT + t0) * HH + lane * 8;

    #pragma unroll 2
    for (int rr = 0; rr < ROWS_PER_WAVE / 2; ++rr) {
        const float* pA = baseA + (size_t)(2 * rr) * HH;
        const float* pB = pA + HH;
        const f32x4 a0 = ntload(pA);
        const f32x4 a1 = ntload(pA + 4);
        const f32x4 b0 = ntload(pB);
        const f32x4 b1 = ntload(pB + 4);

        // two rows' dots: 4 independent fma chains
        float dA0 = a0.x * d0.x, dA1 = a1.x * d1.x;
        float dB0 = b0.x * d0.x, dB1 = b1.x * d1.x;
        dA0 = fmaf(a0.y, d0.y, dA0); dA1 = fmaf(a1.y, d1.y, dA1);
        dB0 = fmaf(b0.y, d0.y, dB0); dB1 = fmaf(b1.y, d1.y, dB1);
        dA0 = fmaf(a0.z, d0.z, dA0); dA1 = fmaf(a1.z, d1.z, dA1);
        dB0 = fmaf(b0.z, d0.z, dB0); dB1 = fmaf(b1.z, d1.z, dB1);
        dA0 = fmaf(a0.w, d0.w, dA0); dA1 = fmaf(a1.w, d1.w, dA1);
        dB0 = fmaf(b0.w, d0.w, dB0); dB1 = fmaf(b1.w, d1.w, dB1);
        float dA = dA0 + dA1;
        float dB = dB0 + dB1;

        // interleaved butterflies (independent chains -> overlapped latency)
        #pragma unroll
        for (int off = 32; off >= 1; off >>= 1) {
            dA += __shfl_xor(dA, off, 64);
            dB += __shfl_xor(dB, off, 64);
        }

        const int tl = wave * ROWS_PER_WAVE + 2 * rr;
        const float paxA = dA + s_loc[tl];
        const float paxB = dB + s_loc[tl + 1];
        if (lane == 0) { s_pax[tl] = paxA; s_pax[tl + 1] = paxB; }

        // online softmax, row A (paxA wave-uniform -> non-divergent branch)
        if (paxA <= m) {
            const float p = __expf(paxA - m);
            l += p;
            acc[0] = fmaf(p, a0.x, acc[0]); acc[1] = fmaf(p, a0.y, acc[1]);
            acc[2] = fmaf(p, a0.z, acc[2]); acc[3] = fmaf(p, a0.w, acc[3]);
            acc[4] = fmaf(p, a1.x, acc[4]); acc[5] = fmaf(p, a1.y, acc[5]);
            acc[6] = fmaf(p, a1.z, acc[6]); acc[7] = fmaf(p, a1.w, acc[7]);
        } else {
            const float sc = __expf(m - paxA);   // first iter: exp(-inf)=0
            l = fmaf(l, sc, 1.0f);
            acc[0] = fmaf(acc[0], sc, a0.x); acc[1] = fmaf(acc[1], sc, a0.y);
            acc[2] = fmaf(acc[2], sc, a0.z); acc[3] = fmaf(acc[3], sc, a0.w);
            acc[4] = fmaf(acc[4], sc, a1.x); acc[5] = fmaf(acc[5], sc, a1.y);
            acc[6] = fmaf(acc[6], sc, a1.z); acc[7] = fmaf(acc[7], sc, a1.w);
            m = paxA;
        }
        // row B
        if (paxB <= m) {
            const float p = __expf(paxB - m);
            l += p;
            acc[0] = fmaf(p, b0.x, acc[0]); acc[1] = fmaf(p, b0.y, acc[1]);
            acc[2] = fmaf(p, b0.z, acc[2]); acc[3] = fmaf(p, b0.w, acc[3]);
            acc[4] = fmaf(p, b1.x, acc[4]); acc[5] = fmaf(p, b1.y, acc[5]);
            acc[6] = fmaf(p, b1.z, acc[6]); acc[7] = fmaf(p, b1.w, acc[7]);
        } else {
            const float sc = __expf(m - paxB);
            l = fmaf(l, sc, 1.0f);
            acc[0] = fmaf(acc[0], sc, b0.x); acc[1] = fmaf(acc[1], sc, b0.y);
            acc[2] = fmaf(acc[2], sc, b0.z); acc[3] = fmaf(acc[3], sc, b0.w);
            acc[4] = fmaf(acc[4], sc, b1.x); acc[5] = fmaf(acc[5], sc, b1.y);
            acc[6] = fmaf(acc[6], sc, b1.z); acc[7] = fmaf(acc[7], sc, b1.w);
            m = paxB;
        }
    }

    // wave partial -> LDS
    float4* ra = (float4*)&red_acc[wave][lane * 8];
    ra[0] = make_float4(acc[0], acc[1], acc[2], acc[3]);
    ra[1] = make_float4(acc[4], acc[5], acc[6], acc[7]);
    if (lane == 0) { red_m[wave] = m; red_l[wave] = l; }
    __syncthreads();

    // coalesced pax store (one 256B store per block)
    if (tid < TCHUNK)
        pax_ws[(size_t)b * TT + c * TCHUNK + tid] = s_pax[tid];

    // wave 0 combines the 4 wave partials -> one block partial
    if (wave == 0) {
        const float M = fmaxf(fmaxf(red_m[0], red_m[1]), fmaxf(red_m[2], red_m[3]));
        float L = 0.0f;
        float o[8];
        #pragma unroll
        for (int j = 0; j < 8; ++j) o[j] = 0.0f;
        #pragma unroll
        for (int w = 0; w < NWAVES; ++w) {
            const float s = __expf(red_m[w] - M);
            L = fmaf(red_l[w], s, L);
            #pragma unroll
            for (int j = 0; j < 8; ++j)
                o[j] = fmaf(red_acc[w][lane * 8 + j], s, o[j]);
        }
        if (lane == 0) { part_m[bid] = M; part_l[bid] = L; }
        float4* pa = (float4*)(part_acc + (size_t)bid * HH + lane * 8);
        pa[0] = make_float4(o[0], o[1], o[2], o[3]);
        pa[1] = make_float4(o[4], o[5], o[6], o[7]);
    }
}

// Pass 2: 8 blocks per batch. Combine the 64 chunk-partials; block j of a
// batch writes sx[j*64 : j*64+64] and a[j*512 : j*512+512].
__global__ __launch_bounds__(256) void attn_pass2(
    const float* __restrict__ pax_ws, const float* __restrict__ part_m,
    const float* __restrict__ part_l, const float* __restrict__ part_acc,
    float* __restrict__ out_sx, float* __restrict__ out_a)
{
    const int b   = blockIdx.x >> 3;
    const int j   = blockIdx.x & 7;
    const int tid = threadIdx.x;

    __shared__ float sm_s[NCHUNK], sw[NCHUNK], slw[NCHUNK];
    __shared__ float sred[4][64];

    if (tid < NCHUNK) sm_s[tid] = part_m[b * NCHUNK + tid];
    __syncthreads();

    float M = -FLT_MAX;
    #pragma unroll
    for (int i = 0; i < NCHUNK; ++i) M = fmaxf(M, sm_s[i]);

    if (tid < NCHUNK) {
        const float w = __expf(sm_s[tid] - M);
        sw[tid]  = w;
        slw[tid] = part_l[b * NCHUNK + tid] * w;
    }
    __syncthreads();

    float L = 0.0f;
    #pragma unroll
    for (int i = 0; i < NCHUNK; ++i) L += slw[i];
    const float invL = 1.0f / L;

    // sx slice: h = j*64 + hh; 4 thread-groups each sum 16 chunks
    const int c  = tid >> 6;
    const int hh = tid & 63;
    const int h  = j * 64 + hh;
    float v = 0.0f;
    #pragma unroll
    for (int i = c * 16; i < c * 16 + 16; ++i)
        v = fmaf(part_acc[((size_t)b * NCHUNK + i) * HH + h], sw[i], v);
    sred[c][hh] = v;
    __syncthreads();
    if (tid < 64)
        out_sx[b * HH + j * 64 + tid] =
            (sred[0][tid] + sred[1][tid] + sred[2][tid] + sred[3][tid]) * invL;

    // a slice: t = j*512 .. j*512+511
    #pragma unroll
    for (int q = 0; q < 2; ++q) {
        const int t = j * 512 + q * 256 + tid;
        out_a[(size_t)b * TT + t] = __expf(pax_ws[(size_t)b * TT + t] - M) * invL;
    }
}

extern "C" void kernel_launch(void* const* d_in, const int* in_sizes, int n_in,
                              void* d_out, int out_size, void* d_ws, size_t ws_size,
                              hipStream_t stream) {
    const float* eh     = (const float*)d_in[0];
    const float* dhx    = (const float*)d_in[1];
    const float* ax     = (const float*)d_in[2];
    const float* conv_w = (const float*)d_in[3];
    const float* conv_b = (const float*)d_in[4];

    float* out    = (float*)d_out;
    float* out_sx = out;                 // B*H = 16384 floats
    float* out_a  = out + BB * HH;       // B*T = 131072 floats

    // workspace layout (floats): pax[B*T] | part_m[B*64] | part_l[B*64] | part_acc[B*64*H]
    float* pax_ws   = (float*)d_ws;
    float* part_m   = pax_ws + (size_t)BB * TT;
    float* part_l   = part_m + BB * NCHUNK;
    float* part_acc = part_l + BB * NCHUNK;

    attn_pass1<<<BB * NCHUNK, 256, 0, stream>>>(eh, dhx, ax, conv_w, conv_b,
                                                pax_ws, part_m, part_l, part_acc);
    attn_pass2<<<BB * 8, 256, 0, stream>>>(pax_ws, part_m, part_l, part_acc,
                                           out_sx, out_a);
}

// Round 4
// 49.177 us; speedup vs baseline: 1.3712x; 1.3712x over previous
//
#include <hip/hip_runtime.h>
#include <cfloat>

#define BB 32
#define TT 4096
#define HH 512
#define KSZ 11
#define PAD 5
#define TCHUNK 64
#define NCHUNK (TT / TCHUNK)             // 64
#define NWAVES 4
#define ROWS_PER_WAVE (TCHUNK / NWAVES)  // 16

typedef float f32x4 __attribute__((ext_vector_type(4)));

// Pass 1: per (batch, T-chunk) block. Computes pax (stores to ws), and an
// online-softmax partial (m, l, acc[H]) over its chunk, combined across the
// block's 4 waves into one partial per block.
__global__ __launch_bounds__(256, 8) void attn_pass1(
    const float* __restrict__ eh, const float* __restrict__ dhx,
    const float* __restrict__ ax, const float* __restrict__ conv_w,
    const float* __restrict__ conv_b,
    float* __restrict__ pax_ws, float* __restrict__ part_m,
    float* __restrict__ part_l, float* __restrict__ part_acc)
{
    const int bid  = blockIdx.x;
    const int b    = bid / NCHUNK;
    const int c    = bid % NCHUNK;
    const int tid  = threadIdx.x;
    const int wave = tid >> 6;
    const int lane = tid & 63;

    __shared__ float s_loc[TCHUNK];
    __shared__ float s_pax[TCHUNK];
    __shared__ float red_m[NWAVES], red_l[NWAVES];
    __shared__ float red_acc[NWAVES][HH];   // 8 KB

    // location bias (11-tap 'same' cross-correlation) for this chunk
    if (tid < TCHUNK) {
        const int t = c * TCHUNK + tid;
        float locv = conv_b[0];
        #pragma unroll
        for (int k = 0; k < KSZ; ++k) {
            const int ts = t + k - PAD;
            const float v = (ts >= 0 && ts < TT) ? ax[b * TT + ts] : 0.0f;
            locv = fmaf(v, conv_w[k], locv);
        }
        s_loc[tid] = locv;
    }

    // per-lane dhx fragment: h = lane*8 .. lane*8+7
    const float* dpp = dhx + (size_t)b * HH + lane * 8;
    const f32x4 d0 = *(const f32x4*)dpp;
    const f32x4 d1 = *(const f32x4*)(dpp + 4);

    __syncthreads();

    float m = -FLT_MAX, l = 0.0f;
    float acc[8];
    #pragma unroll
    for (int j = 0; j < 8; ++j) acc[j] = 0.0f;

    const int t0 = c * TCHUNK + wave * ROWS_PER_WAVE;
    const float* base = eh + ((size_t)b * TT + t0) * HH + lane * 8;

    // process one row (data in e0,e1), row-local index tl within chunk
    auto process = [&](const f32x4 e0, const f32x4 e1, const int tl) {
        float da = e0.x * d0.x;
        float db = e1.x * d1.x;
        da = fmaf(e0.y, d0.y, da);  db = fmaf(e1.y, d1.y, db);
        da = fmaf(e0.z, d0.z, da);  db = fmaf(e1.z, d1.z, db);
        da = fmaf(e0.w, d0.w, da);  db = fmaf(e1.w, d1.w, db);
        float dot = da + db;
        #pragma unroll
        for (int off = 32; off >= 1; off >>= 1)
            dot += __shfl_xor(dot, off, 64);

        const float paxv = dot + s_loc[tl];
        if (lane == 0) s_pax[tl] = paxv;

        // online softmax; paxv is wave-uniform so this branch is non-divergent
        if (paxv <= m) {
            const float p = __expf(paxv - m);
            l += p;
            acc[0] = fmaf(p, e0.x, acc[0]); acc[1] = fmaf(p, e0.y, acc[1]);
            acc[2] = fmaf(p, e0.z, acc[2]); acc[3] = fmaf(p, e0.w, acc[3]);
            acc[4] = fmaf(p, e1.x, acc[4]); acc[5] = fmaf(p, e1.y, acc[5]);
            acc[6] = fmaf(p, e1.z, acc[6]); acc[7] = fmaf(p, e1.w, acc[7]);
        } else {
            const float sc = __expf(m - paxv);   // first iter: exp(-inf)=0
            l = fmaf(l, sc, 1.0f);
            acc[0] = fmaf(acc[0], sc, e0.x); acc[1] = fmaf(acc[1], sc, e0.y);
            acc[2] = fmaf(acc[2], sc, e0.z); acc[3] = fmaf(acc[3], sc, e0.w);
            acc[4] = fmaf(acc[4], sc, e1.x); acc[5] = fmaf(acc[5], sc, e1.y);
            acc[6] = fmaf(acc[6], sc, e1.z); acc[7] = fmaf(acc[7], sc, e1.w);
            m = paxv;
        }
    };

    // depth-1 software prefetch: row r+1's loads are in flight while row r
    // computes (dot+butterfly+exp+acc ~300cy hides under ~900cy HBM latency)
    f32x4 cur0 = *(const f32x4*)base;
    f32x4 cur1 = *(const f32x4*)(base + 4);
    for (int r = 0; r < ROWS_PER_WAVE - 1; ++r) {
        const float* pn = base + (size_t)(r + 1) * HH;
        const f32x4 nxt0 = *(const f32x4*)pn;
        const f32x4 nxt1 = *(const f32x4*)(pn + 4);
        process(cur0, cur1, wave * ROWS_PER_WAVE + r);
        cur0 = nxt0;
        cur1 = nxt1;
    }
    process(cur0, cur1, wave * ROWS_PER_WAVE + ROWS_PER_WAVE - 1);

    // wave partial -> LDS
    float4* ra = (float4*)&red_acc[wave][lane * 8];
    ra[0] = make_float4(acc[0], acc[1], acc[2], acc[3]);
    ra[1] = make_float4(acc[4], acc[5], acc[6], acc[7]);
    if (lane == 0) { red_m[wave] = m; red_l[wave] = l; }
    __syncthreads();

    // coalesced pax store (one 256B store per block)
    if (tid < TCHUNK)
        pax_ws[(size_t)b * TT + c * TCHUNK + tid] = s_pax[tid];

    // wave 0 combines the 4 wave partials -> one block partial
    if (wave == 0) {
        const float M = fmaxf(fmaxf(red_m[0], red_m[1]), fmaxf(red_m[2], red_m[3]));
        float L = 0.0f;
        float o[8];
        #pragma unroll
        for (int j = 0; j < 8; ++j) o[j] = 0.0f;
        #pragma unroll
        for (int w = 0; w < NWAVES; ++w) {
            const float s = __expf(red_m[w] - M);
            L = fmaf(red_l[w], s, L);
            #pragma unroll
            for (int j = 0; j < 8; ++j)
                o[j] = fmaf(red_acc[w][lane * 8 + j], s, o[j]);
        }
        if (lane == 0) { part_m[bid] = M; part_l[bid] = L; }
        float4* pa = (float4*)(part_acc + (size_t)bid * HH + lane * 8);
        pa[0] = make_float4(o[0], o[1], o[2], o[3]);
        pa[1] = make_float4(o[4], o[5], o[6], o[7]);
    }
}

// Pass 2: 8 blocks per batch. Combine the 64 chunk-partials; block j of a
// batch writes sx[j*64 : j*64+64] and a[j*512 : j*512+512].
__global__ __launch_bounds__(256) void attn_pass2(
    const float* __restrict__ pax_ws, const float* __restrict__ part_m,
    const float* __restrict__ part_l, const float* __restrict__ part_acc,
    float* __restrict__ out_sx, float* __restrict__ out_a)
{
    const int b   = blockIdx.x >> 3;
    const int j   = blockIdx.x & 7;
    const int tid = threadIdx.x;

    __shared__ float sm_s[NCHUNK], sw[NCHUNK], slw[NCHUNK];
    __shared__ float sred[4][64];

    if (tid < NCHUNK) sm_s[tid] = part_m[b * NCHUNK + tid];
    __syncthreads();

    float M = -FLT_MAX;
    #pragma unroll
    for (int i = 0; i < NCHUNK; ++i) M = fmaxf(M, sm_s[i]);

    if (tid < NCHUNK) {
        const float w = __expf(sm_s[tid] - M);
        sw[tid]  = w;
        slw[tid] = part_l[b * NCHUNK + tid] * w;
    }
    __syncthreads();

    float L = 0.0f;
    #pragma unroll
    for (int i = 0; i < NCHUNK; ++i) L += slw[i];
    const float invL = 1.0f / L;

    // sx slice: h = j*64 + hh; 4 thread-groups each sum 16 chunks
    const int c  = tid >> 6;
    const int hh = tid & 63;
    const int h  = j * 64 + hh;
    float v = 0.0f;
    #pragma unroll
    for (int i = c * 16; i < c * 16 + 16; ++i)
        v = fmaf(part_acc[((size_t)b * NCHUNK + i) * HH + h], sw[i], v);
    sred[c][hh] = v;
    __syncthreads();
    if (tid < 64)
        out_sx[b * HH + j * 64 + tid] =
            (sred[0][tid] + sred[1][tid] + sred[2][tid] + sred[3][tid]) * invL;

    // a slice: t = j*512 .. j*512+511
    #pragma unroll
    for (int q = 0; q < 2; ++q) {
        const int t = j * 512 + q * 256 + tid;
        out_a[(size_t)b * TT + t] = __expf(pax_ws[(size_t)b * TT + t] - M) * invL;
    }
}

extern "C" void kernel_launch(void* const* d_in, const int* in_sizes, int n_in,
                              void* d_out, int out_size, void* d_ws, size_t ws_size,
                              hipStream_t stream) {
    const float* eh     = (const float*)d_in[0];
    const float* dhx    = (const float*)d_in[1];
    const float* ax     = (const float*)d_in[2];
    const float* conv_w = (const float*)d_in[3];
    const float* conv_b = (const float*)d_in[4];

    float* out    = (float*)d_out;
    float* out_sx = out;                 // B*H = 16384 floats
    float* out_a  = out + BB * HH;       // B*T = 131072 floats

    // workspace layout (floats): pax[B*T] | part_m[B*64] | part_l[B*64] | part_acc[B*64*H]
    float* pax_ws   = (float*)d_ws;
    float* part_m   = pax_ws + (size_t)BB * TT;
    float* part_l   = part_m + BB * NCHUNK;
    float* part_acc = part_l + BB * NCHUNK;

    attn_pass1<<<BB * NCHUNK, 256, 0, stream>>>(eh, dhx, ax, conv_w, conv_b,
                                                pax_ws, part_m, part_l, part_acc);
    attn_pass2<<<BB * 8, 256, 0, stream>>>(pax_ws, part_m, part_l, part_acc,
                                           out_sx, out_a);
}

// Round 5
// 48.320 us; speedup vs baseline: 1.3955x; 1.0177x over previous
//
#include <hip/hip_runtime.h>
#include <cfloat>

#define BB 32
#define TT 4096
#define HH 512
#define KSZ 11
#define PAD 5
#define TCHUNK 64
#define NCHUNK (TT / TCHUNK)             // 64
#define NWAVES 4
#define ROWS_PER_WAVE (TCHUNK / NWAVES)  // 16

typedef float f32x4 __attribute__((ext_vector_type(4)));
typedef float f32x2 __attribute__((ext_vector_type(2)));

// Pass 1: per (batch, T-chunk) block. Computes pax (stores to ws), and an
// online-softmax partial (m, l, acc[H]) over its chunk, combined across the
// block's 4 waves into one partial per block.
__global__ __launch_bounds__(256, 8) void attn_pass1(
    const float* __restrict__ eh, const float* __restrict__ dhx,
    const float* __restrict__ ax, const float* __restrict__ conv_w,
    const float* __restrict__ conv_b,
    float* __restrict__ pax_ws, float* __restrict__ part_m,
    float* __restrict__ part_l, float* __restrict__ part_acc)
{
    const int bid  = blockIdx.x;
    const int b    = bid / NCHUNK;
    const int c    = bid % NCHUNK;
    const int tid  = threadIdx.x;
    const int wave = tid >> 6;
    const int lane = tid & 63;

    __shared__ float s_loc[TCHUNK];
    __shared__ float s_pax[TCHUNK];
    __shared__ float red_m[NWAVES], red_l[NWAVES];
    __shared__ float red_acc[NWAVES][HH];   // 8 KB

    const int t0 = c * TCHUNK + wave * ROWS_PER_WAVE;
    const float* base = eh + ((size_t)b * TT + t0) * HH + lane * 8;

    // issue row-0 eh loads + dhx loads FIRST: their latency hides under the
    // conv preamble + barrier below
    f32x4 cur0 = *(const f32x4*)base;
    f32x4 cur1 = *(const f32x4*)(base + 4);
    const float* dpp = dhx + (size_t)b * HH + lane * 8;
    const f32x4 d0 = *(const f32x4*)dpp;
    const f32x4 d1 = *(const f32x4*)(dpp + 4);

    // location bias (11-tap 'same' cross-correlation) for this chunk
    if (tid < TCHUNK) {
        const int t = c * TCHUNK + tid;
        float locv = conv_b[0];
        #pragma unroll
        for (int k = 0; k < KSZ; ++k) {
            const int ts = t + k - PAD;
            const float v = (ts >= 0 && ts < TT) ? ax[b * TT + ts] : 0.0f;
            locv = fmaf(v, conv_w[k], locv);
        }
        s_loc[tid] = locv;
    }

    __syncthreads();

    float m = -FLT_MAX, l = 0.0f;
    float acc[8];
    #pragma unroll
    for (int j = 0; j < 8; ++j) acc[j] = 0.0f;

    // process one row (data in e0,e1), row-local index tl within chunk
    auto process = [&](const f32x4 e0, const f32x4 e1, const int tl) {
        float da = e0.x * d0.x;
        float db = e1.x * d1.x;
        da = fmaf(e0.y, d0.y, da);  db = fmaf(e1.y, d1.y, db);
        da = fmaf(e0.z, d0.z, da);  db = fmaf(e1.z, d1.z, db);
        da = fmaf(e0.w, d0.w, da);  db = fmaf(e1.w, d1.w, db);
        float dot = da + db;
        #pragma unroll
        for (int off = 32; off >= 1; off >>= 1)
            dot += __shfl_xor(dot, off, 64);

        const float paxv = dot + s_loc[tl];
        if (lane == 0) s_pax[tl] = paxv;

        // online softmax; paxv is wave-uniform so this branch is non-divergent
        if (paxv <= m) {
            const float p = __expf(paxv - m);
            l += p;
            acc[0] = fmaf(p, e0.x, acc[0]); acc[1] = fmaf(p, e0.y, acc[1]);
            acc[2] = fmaf(p, e0.z, acc[2]); acc[3] = fmaf(p, e0.w, acc[3]);
            acc[4] = fmaf(p, e1.x, acc[4]); acc[5] = fmaf(p, e1.y, acc[5]);
            acc[6] = fmaf(p, e1.z, acc[6]); acc[7] = fmaf(p, e1.w, acc[7]);
        } else {
            const float sc = __expf(m - paxv);   // first iter: exp(-inf)=0
            l = fmaf(l, sc, 1.0f);
            acc[0] = fmaf(acc[0], sc, e0.x); acc[1] = fmaf(acc[1], sc, e0.y);
            acc[2] = fmaf(acc[2], sc, e0.z); acc[3] = fmaf(acc[3], sc, e0.w);
            acc[4] = fmaf(acc[4], sc, e1.x); acc[5] = fmaf(acc[5], sc, e1.y);
            acc[6] = fmaf(acc[6], sc, e1.z); acc[7] = fmaf(acc[7], sc, e1.w);
            m = paxv;
        }
    };

    // depth-1 software prefetch: row r+1's loads are in flight while row r
    // computes (dot+butterfly+exp+acc hides under HBM latency)
    for (int r = 0; r < ROWS_PER_WAVE - 1; ++r) {
        const float* pn = base + (size_t)(r + 1) * HH;
        const f32x4 nxt0 = *(const f32x4*)pn;
        const f32x4 nxt1 = *(const f32x4*)(pn + 4);
        process(cur0, cur1, wave * ROWS_PER_WAVE + r);
        cur0 = nxt0;
        cur1 = nxt1;
    }
    process(cur0, cur1, wave * ROWS_PER_WAVE + ROWS_PER_WAVE - 1);

    // wave partial -> LDS
    float4* ra = (float4*)&red_acc[wave][lane * 8];
    ra[0] = make_float4(acc[0], acc[1], acc[2], acc[3]);
    ra[1] = make_float4(acc[4], acc[5], acc[6], acc[7]);
    if (lane == 0) { red_m[wave] = m; red_l[wave] = l; }
    __syncthreads();

    // coalesced pax store (one 256B store per block)
    if (tid < TCHUNK)
        pax_ws[(size_t)b * TT + c * TCHUNK + tid] = s_pax[tid];

    // wave 0 combines the 4 wave partials -> one block partial
    if (wave == 0) {
        const float M = fmaxf(fmaxf(red_m[0], red_m[1]), fmaxf(red_m[2], red_m[3]));
        float L = 0.0f;
        float o[8];
        #pragma unroll
        for (int j = 0; j < 8; ++j) o[j] = 0.0f;
        #pragma unroll
        for (int w = 0; w < NWAVES; ++w) {
            const float s = __expf(red_m[w] - M);
            L = fmaf(red_l[w], s, L);
            #pragma unroll
            for (int j = 0; j < 8; ++j)
                o[j] = fmaf(red_acc[w][lane * 8 + j], s, o[j]);
        }
        if (lane == 0) { part_m[bid] = M; part_l[bid] = L; }
        float4* pa = (float4*)(part_acc + (size_t)bid * HH + lane * 8);
        pa[0] = make_float4(o[0], o[1], o[2], o[3]);
        pa[1] = make_float4(o[4], o[5], o[6], o[7]);
    }
}

// Pass 2: 8 blocks per batch. Combine the 64 chunk-partials; block j of a
// batch writes sx[j*64 : j*64+64] and a[j*512 : j*512+512].
__global__ __launch_bounds__(256) void attn_pass2(
    const float* __restrict__ pax_ws, const float* __restrict__ part_m,
    const float* __restrict__ part_l, const float* __restrict__ part_acc,
    float* __restrict__ out_sx, float* __restrict__ out_a)
{
    const int b   = blockIdx.x >> 3;
    const int j   = blockIdx.x & 7;
    const int tid = threadIdx.x;

    __shared__ float sm_s[NCHUNK], sw[NCHUNK], slw[NCHUNK];
    __shared__ float sred[4][64];

    // ---- issue ALL global loads first: latency hides under the M/L phase ----
    // part_acc slice: thread (c,hh) sums chunks c*16..c*16+15 for h=j*64+hh
    const int c  = tid >> 6;
    const int hh = tid & 63;
    const int h  = j * 64 + hh;
    float pa[16];
    #pragma unroll
    for (int i = 0; i < 16; ++i)
        pa[i] = part_acc[((size_t)b * NCHUNK + c * 16 + i) * HH + h];

    // pax slice for 'a': float2 per thread covers 512 t-values
    const int ta = j * 512 + tid * 2;
    const f32x2 px = *(const f32x2*)(pax_ws + (size_t)b * TT + ta);

    if (tid < NCHUNK) sm_s[tid] = part_m[b * NCHUNK + tid];
    __syncthreads();

    // ---- M via 4-way tree (breaks the 64-deep serial fmax chain) ----
    float M0 = sm_s[0], M1 = sm_s[1], M2 = sm_s[2], M3 = sm_s[3];
    #pragma unroll
    for (int i = 4; i < NCHUNK; i += 4) {
        M0 = fmaxf(M0, sm_s[i]);     M1 = fmaxf(M1, sm_s[i + 1]);
        M2 = fmaxf(M2, sm_s[i + 2]); M3 = fmaxf(M3, sm_s[i + 3]);
    }
    const float M = fmaxf(fmaxf(M0, M1), fmaxf(M2, M3));

    if (tid < NCHUNK) {
        const float w = __expf(sm_s[tid] - M);
        sw[tid]  = w;
        slw[tid] = part_l[b * NCHUNK + tid] * w;
    }
    __syncthreads();

    float L0 = slw[0], L1 = slw[1], L2 = slw[2], L3 = slw[3];
    #pragma unroll
    for (int i = 4; i < NCHUNK; i += 4) {
        L0 += slw[i];     L1 += slw[i + 1];
        L2 += slw[i + 2]; L3 += slw[i + 3];
    }
    const float invL = 1.0f / ((L0 + L1) + (L2 + L3));

    // ---- sx ----
    float v = 0.0f;
    #pragma unroll
    for (int i = 0; i < 16; ++i)
        v = fmaf(pa[i], sw[c * 16 + i], v);
    sred[c][hh] = v;
    __syncthreads();
    if (tid < 64)
        out_sx[b * HH + j * 64 + tid] =
            (sred[0][tid] + sred[1][tid] + sred[2][tid] + sred[3][tid]) * invL;

    // ---- a (vectorized float2) ----
    f32x2 av;
    av.x = __expf(px.x - M) * invL;
    av.y = __expf(px.y - M) * invL;
    *(f32x2*)(out_a + (size_t)b * TT + ta) = av;
}

extern "C" void kernel_launch(void* const* d_in, const int* in_sizes, int n_in,
                              void* d_out, int out_size, void* d_ws, size_t ws_size,
                              hipStream_t stream) {
    const float* eh     = (const float*)d_in[0];
    const float* dhx    = (const float*)d_in[1];
    const float* ax     = (const float*)d_in[2];
    const float* conv_w = (const float*)d_in[3];
    const float* conv_b = (const float*)d_in[4];

    float* out    = (float*)d_out;
    float* out_sx = out;                 // B*H = 16384 floats
    float* out_a  = out + BB * HH;       // B*T = 131072 floats

    // workspace layout (floats): pax[B*T] | part_m[B*64] | part_l[B*64] | part_acc[B*64*H]
    float* pax_ws   = (float*)d_ws;
    float* part_m   = pax_ws + (size_t)BB * TT;
    float* part_l   = part_m + BB * NCHUNK;
    float* part_acc = part_l + BB * NCHUNK;

    attn_pass1<<<BB * NCHUNK, 256, 0, stream>>>(eh, dhx, ax, conv_w, conv_b,
                                                pax_ws, part_m, part_l, part_acc);
    attn_pass2<<<BB * 8, 256, 0, stream>>>(pax_ws, part_m, part_l, part_acc,
                                           out_sx, out_a);
}